// Round 9
// baseline (307.209 us; speedup 1.0000x reference)
//
#include <hip/hip_runtime.h>

#define LOG2E 1.44269504088896340736f

typedef short    short8  __attribute__((ext_vector_type(8)));
typedef float    floatx4 __attribute__((ext_vector_type(4)));
typedef unsigned uintx4  __attribute__((ext_vector_type(4)));

__device__ __forceinline__ unsigned pk_bf16(float lo, float hi) {
    unsigned r;
    asm("v_cvt_pk_bf16_f32 %0, %1, %2" : "=v"(r) : "v"(lo), "v"(hi));
    return r;
}
__device__ __forceinline__ float sigm(float v) {
    return __builtin_amdgcn_rcpf(1.0f + __builtin_amdgcn_exp2f(-LOG2E * v));
}
__device__ __forceinline__ float tanhx(float v) {
    return 1.0f - 2.0f * __builtin_amdgcn_rcpf(1.0f + __builtin_amdgcn_exp2f(2.0f * LOG2E * v));
}

// One-barrier MFMA LSTM, r-split cell update. Grid 256 x 4 waves, 8 batches/block.
// gates[g,m] = W_hh[g,:] @ h[:,m] + bias (bias = constant MFMA C-input).
// Wave U owns units [16U,16U+16) for all 4 gate classes (t4-tiles).
// Post-MFMA, lane pair (l15, l15+8) splits the 4 r-rows of REAL batch m=l15&7:
//   lower lane keeps r={0,1}, upper lane takes r={2,3} via shfl_xor(8).
// -> every lane updates exactly 2 real cells (10 trans) — no pad-slot waste.
// x*W_ih added post-shuffle per cell. One ds_write_b32/lane, one barrier/step.
__global__ void __launch_bounds__(256, 1)
lstm_mfma(const float* __restrict__ x,      // [2048,512]
          const float* __restrict__ W_ih,   // [256]
          const float* __restrict__ W_hh,   // [256,64]
          const float* __restrict__ b_ih,   // [256]
          const float* __restrict__ b_hh,   // [256]
          const float* __restrict__ W_fc,   // [2,64]
          const float* __restrict__ b_fc,   // [2]
          float* __restrict__ out)          // [2048,2]
{
    __shared__ unsigned hlds[2 * 16 * 32];  // 2 bufs: 16 rows(batch) x 64 bf16(u)
    __shared__ float    red[4][8][2];       // FC cross-wave reduce

    const int tid  = threadIdx.x;
    const int U    = tid >> 6;              // wave 0..3 (u-block)
    const int lane = tid & 63;
    const int l15  = lane & 15;
    const int lq   = lane >> 4;
    const int half = l15 >> 3;              // 0: keep r{0,1}; 1: take r{2,3}
    const int m    = l15 & 7;               // real batch index
    const int b0   = blockIdx.x * 8;

    // zero both h buffers (pad rows 8-15 stay zero forever)
    #pragma unroll
    for (int i = 0; i < 4; ++i) hlds[tid + 256 * i] = 0u;

    // ---- A fragments: W_hh rows bf16. lane: tile-row=l15, k=32f+8lq+e ----
    short8 wfrag[4][2];
    #pragma unroll
    for (int t4 = 0; t4 < 4; ++t4) {
        const int grow = t4 * 64 + U * 16 + l15;
        #pragma unroll
        for (int f = 0; f < 2; ++f) {
            const float* p = W_hh + grow * 64 + 32 * f + 8 * lq;
            uintx4 uv;
            uv.x = pk_bf16(p[0], p[1]);
            uv.y = pk_bf16(p[2], p[3]);
            uv.z = pk_bf16(p[4], p[5]);
            uv.w = pk_bf16(p[6], p[7]);
            wfrag[t4][f] = __builtin_bit_cast(short8, uv);
        }
    }
    // ---- bias as constant MFMA C-input: biasC[t4][r], g = 64t4+16U+4lq+r ----
    floatx4 biasC[4];
    #pragma unroll
    for (int t4 = 0; t4 < 4; ++t4)
        #pragma unroll
        for (int r = 0; r < 4; ++r) {
            const int g = t4 * 64 + U * 16 + 4 * lq + r;
            biasC[t4][r] = b_ih[g] + b_hh[g];
        }
    // ---- per-cell W_ih for this lane's 2 cells: r = 2*half + z ----
    float wihp[4][2];
    #pragma unroll
    for (int t4 = 0; t4 < 4; ++t4)
        #pragma unroll
        for (int z = 0; z < 2; ++z)
            wihp[t4][z] = W_ih[t4 * 64 + U * 16 + 4 * lq + 2 * half + z];

    // ---- LDS addressing (word-index XOR swizzle; R8-validated reads) ----
    const int swzr = (l15 & 7) << 2;
    const uintx4* rd00 = (const uintx4*)&hlds[      l15 * 32 + (( 0 + 4 * lq) ^ swzr)];
    const uintx4* rd01 = (const uintx4*)&hlds[      l15 * 32 + ((16 + 4 * lq) ^ swzr)];
    const uintx4* rd10 = (const uintx4*)&hlds[512 + l15 * 32 + (( 0 + 4 * lq) ^ swzr)];
    const uintx4* rd11 = (const uintx4*)&hlds[512 + l15 * 32 + ((16 + 4 * lq) ^ swzr)];
    // write: row m, word (8U + 2lq + half) ^ (m<<2)  — exactly 2-way banked (free)
    unsigned* wr0 = &hlds[      m * 32 + ((8 * U + 2 * lq + half) ^ (m << 2))];
    unsigned* wr1 = &hlds[512 + m * 32 + ((8 * U + 2 * lq + half) ^ (m << 2))];

    float c[2]  = {0.f, 0.f};
    float hq[2] = {0.f, 0.f};

    const float* xrow = x + (long)(b0 + m) * 512;
    float xv = xrow[0];                      // current-step x (prefetched)

    __syncthreads();

#define STEP(RD0, RD1, WRP, T) do {                                              \
    const int   tn  = ((T) < 511) ? (T) + 1 : 511;                               \
    const float xnv = xrow[tn];              /* prefetch next step's x */        \
    short8 hb0 = __builtin_bit_cast(short8, *(RD0));                             \
    short8 hb1 = __builtin_bit_cast(short8, *(RD1));                             \
    floatx4 acc[4];                                                              \
    _Pragma("unroll")                                                            \
    for (int t4 = 0; t4 < 4; ++t4) {                                             \
        acc[t4] = __builtin_amdgcn_mfma_f32_16x16x32_bf16(wfrag[t4][0], hb0,     \
                                                          biasC[t4], 0, 0, 0);   \
        acc[t4] = __builtin_amdgcn_mfma_f32_16x16x32_bf16(wfrag[t4][1], hb1,     \
                                                          acc[t4], 0, 0, 0);     \
    }                                                                            \
    /* r-split: upper half-lanes take partner's r={2,3} */                       \
    float a[4][2];                                                               \
    _Pragma("unroll")                                                            \
    for (int t4 = 0; t4 < 4; ++t4) {                                             \
        const float s2 = __shfl_xor(acc[t4][2], 8);                              \
        const float s3 = __shfl_xor(acc[t4][3], 8);                              \
        a[t4][0] = half ? s2 : acc[t4][0];                                       \
        a[t4][1] = half ? s3 : acc[t4][1];                                       \
    }                                                                            \
    _Pragma("unroll")                                                            \
    for (int z = 0; z < 2; ++z) {                                                \
        const float ig = sigm (fmaf(xv, wihp[0][z], a[0][z]));                   \
        const float fg = sigm (fmaf(xv, wihp[1][z], a[1][z]));                   \
        const float gg = tanhx(fmaf(xv, wihp[2][z], a[2][z]));                   \
        const float og = sigm (fmaf(xv, wihp[3][z], a[3][z]));                   \
        c[z]  = fmaf(fg, c[z], ig * gg);                                         \
        hq[z] = og * tanhx(c[z]);                                                \
    }                                                                            \
    *(WRP) = pk_bf16(hq[0], hq[1]);                                              \
    xv = xnv;                                                                    \
    __syncthreads();                                                             \
} while (0)

    for (int t2 = 0; t2 < 512; t2 += 2) {
        STEP(rd00, rd01, wr1, t2);       // read buf0 (h(t-1)), write buf1
        STEP(rd10, rd11, wr0, t2 + 1);   // read buf1,           write buf0
    }
#undef STEP

    // ---- epilogue: out[b0+m,:] = h_T[m,:] @ W_fc.T + b_fc ----
    // lane's cells: u = 16U + 4lq + 2*half + z
    const int u0 = U * 16 + 4 * lq + 2 * half;
    float p0 = fmaf(hq[0], W_fc[u0],      hq[1] * W_fc[u0 + 1]);
    float p1 = fmaf(hq[0], W_fc[64 + u0], hq[1] * W_fc[64 + u0 + 1]);
    // reduce over lq (shfl_down 32,16) then over the half split (xor 8)
    p0 += __shfl_down(p0, 32);  p0 += __shfl_down(p0, 16);  p0 += __shfl_xor(p0, 8);
    p1 += __shfl_down(p1, 32);  p1 += __shfl_down(p1, 16);  p1 += __shfl_xor(p1, 8);
    if (lane < 8) { red[U][lane][0] = p0; red[U][lane][1] = p1; }
    __syncthreads();
    if (tid < 16) {
        const int mm = tid >> 1, cls = tid & 1;
        const float s = red[0][mm][cls] + red[1][mm][cls] +
                        red[2][mm][cls] + red[3][mm][cls] + b_fc[cls];
        out[(b0 + mm) * 2 + cls] = s;
    }
}

extern "C" void kernel_launch(void* const* d_in, const int* in_sizes, int n_in,
                              void* d_out, int out_size, void* d_ws, size_t ws_size,
                              hipStream_t stream) {
    const float* x    = (const float*)d_in[0];
    const float* W_ih = (const float*)d_in[1];
    const float* W_hh = (const float*)d_in[2];
    const float* b_ih = (const float*)d_in[3];
    const float* b_hh = (const float*)d_in[4];
    const float* W_fc = (const float*)d_in[5];
    const float* b_fc = (const float*)d_in[6];
    float* out = (float*)d_out;

    dim3 grid(256);    // 8 batches per block -> 1 block per CU
    dim3 block(256);   // 4 waves
    hipLaunchKernelGGL(lstm_mfma, grid, block, 0, stream,
                       x, W_ih, W_hh, b_ih, b_hh, W_fc, b_fc, out);
}

// Round 12
// 301.239 us; speedup vs baseline: 1.0198x; 1.0198x over previous
//
#include <hip/hip_runtime.h>

#define LOG2E 1.44269504088896340736f

typedef short    short8  __attribute__((ext_vector_type(8)));
typedef float    floatx4 __attribute__((ext_vector_type(4)));
typedef unsigned uintx4  __attribute__((ext_vector_type(4)));

__device__ __forceinline__ unsigned pk_bf16(float lo, float hi) {
    unsigned r;
    asm("v_cvt_pk_bf16_f32 %0, %1, %2" : "=v"(r) : "v"(lo), "v"(hi));
    return r;
}
__device__ __forceinline__ float sigm(float v) {
    return __builtin_amdgcn_rcpf(1.0f + __builtin_amdgcn_exp2f(-LOG2E * v));
}
__device__ __forceinline__ float tanhx(float v) {
    return 1.0f - 2.0f * __builtin_amdgcn_rcpf(1.0f + __builtin_amdgcn_exp2f(2.0f * LOG2E * v));
}

// One-barrier MFMA LSTM, r-split cell update, W in AGPRs consumed directly by
// inline-asm MFMA ("a" operand class). R10 proved W residency was the disease
// (LDS staging: 260us -> 160us); this removes the remaining 8 ds_read_b128 per
// wave per step of W traffic by homing the loop-invariant fragments in AGPRs,
// which gfx950 MFMA reads natively (ISA sec 10). s_nop 7 covers the
// MFMA-D -> VALU-read hazard across the opaque asm boundary.
__global__ void __launch_bounds__(256, 1)
lstm_mfma(const float* __restrict__ x,      // [2048,512]
          const float* __restrict__ W_ih,   // [256]
          const float* __restrict__ W_hh,   // [256,64]
          const float* __restrict__ b_ih,   // [256]
          const float* __restrict__ b_hh,   // [256]
          const float* __restrict__ W_fc,   // [2,64]
          const float* __restrict__ b_fc,   // [2]
          float* __restrict__ out)          // [2048,2]
{
    __shared__ unsigned hlds[2 * 16 * 32];  // 4 KB: 2 bufs, 16 rows x 64 bf16
    __shared__ float    blds[256];          // 1 KB: biasC by (U,t4,lq)
    __shared__ float    red[4][8][2];       // FC cross-wave reduce

    const int tid  = threadIdx.x;
    const int U    = tid >> 6;              // wave 0..3 (u-block)
    const int lane = tid & 63;
    const int l15  = lane & 15;
    const int lq   = lane >> 4;
    const int half = l15 >> 3;              // 0: keep r{0,1}; 1: take r{2,3}
    const int m    = l15 & 7;               // real batch index
    const int b0   = blockIdx.x * 8;

    // zero both h buffers (pad rows 8-15 stay zero forever)
    #pragma unroll
    for (int i = 0; i < 4; ++i) hlds[tid + 256 * i] = 0u;

    // ---- W_hh A-fragments -> AGPR-homed short8 values (used via "a" asm) ----
    // A-frag for tile (U,t4), k-half f: lane holds row=l15, k=32f+8lq+e (e=0..7)
    short8 wf[4][2];
    #pragma unroll
    for (int t4 = 0; t4 < 4; ++t4) {
        const int grow = t4 * 64 + U * 16 + l15;
        #pragma unroll
        for (int f = 0; f < 2; ++f) {
            const float* p = W_hh + grow * 64 + 32 * f + 8 * lq;
            uintx4 uv;
            uv.x = pk_bf16(p[0], p[1]);
            uv.y = pk_bf16(p[2], p[3]);
            uv.z = pk_bf16(p[4], p[5]);
            uv.w = pk_bf16(p[6], p[7]);
            wf[t4][f] = __builtin_bit_cast(short8, uv);
        }
    }
    // ---- stage biasC into LDS: slot (U,t4,lq), r-vector of 4 ----
    #pragma unroll
    for (int t4 = 0; t4 < 4; ++t4) {
        if (l15 == 0) {
            floatx4 bv;
            #pragma unroll
            for (int r = 0; r < 4; ++r) {
                const int g = t4 * 64 + U * 16 + 4 * lq + r;
                bv[r] = b_ih[g] + b_hh[g];
            }
            *(floatx4*)&blds[(U * 16 + t4 * 4 + lq) * 4] = bv;
        }
    }
    // ---- per-cell W_ih for this lane's 2 cells: r = 2*half + z (8 regs) ----
    float wihp[4][2];
    #pragma unroll
    for (int t4 = 0; t4 < 4; ++t4)
        #pragma unroll
        for (int z = 0; z < 2; ++z)
            wihp[t4][z] = W_ih[t4 * 64 + U * 16 + 4 * lq + 2 * half + z];

    // ---- LDS addressing (word-index XOR swizzle; validated R8-R10) ----
    const int swzr = (l15 & 7) << 2;
    const uintx4* rd00 = (const uintx4*)&hlds[      l15 * 32 + (( 0 + 4 * lq) ^ swzr)];
    const uintx4* rd01 = (const uintx4*)&hlds[      l15 * 32 + ((16 + 4 * lq) ^ swzr)];
    const uintx4* rd10 = (const uintx4*)&hlds[512 + l15 * 32 + (( 0 + 4 * lq) ^ swzr)];
    const uintx4* rd11 = (const uintx4*)&hlds[512 + l15 * 32 + ((16 + 4 * lq) ^ swzr)];
    // write: row m, word (8U + 2lq + half) ^ (m<<2) -- exactly 2-way banked (free)
    unsigned* wr0 = &hlds[      m * 32 + ((8 * U + 2 * lq + half) ^ (m << 2))];
    unsigned* wr1 = &hlds[512 + m * 32 + ((8 * U + 2 * lq + half) ^ (m << 2))];

    float c[2]  = {0.f, 0.f};
    float hq[2] = {0.f, 0.f};

    const float* xrow = x + (long)(b0 + m) * 512;
    float xv = xrow[0];                      // current-step x (prefetched)

    __syncthreads();

#define STEP(RD0, RD1, WRP, T) do {                                              \
    const int   tn  = ((T) < 511) ? (T) + 1 : 511;                               \
    const float xnv = xrow[tn];              /* prefetch next step's x */        \
    short8 hb0 = __builtin_bit_cast(short8, *(RD0));                             \
    short8 hb1 = __builtin_bit_cast(short8, *(RD1));                             \
    floatx4 bc[4];                                                               \
    _Pragma("unroll")                                                            \
    for (int t4 = 0; t4 < 4; ++t4)                                               \
        bc[t4] = *(const floatx4*)&blds[(U * 16 + t4 * 4 + lq) * 4];             \
    floatx4 acc0, acc1, acc2, acc3;                                              \
    asm("v_mfma_f32_16x16x32_bf16 %[a0], %[w00], %[h0], %[b0]\n\t"               \
        "v_mfma_f32_16x16x32_bf16 %[a1], %[w10], %[h0], %[b1]\n\t"               \
        "v_mfma_f32_16x16x32_bf16 %[a2], %[w20], %[h0], %[b2]\n\t"               \
        "v_mfma_f32_16x16x32_bf16 %[a3], %[w30], %[h0], %[b3]\n\t"               \
        "v_mfma_f32_16x16x32_bf16 %[a0], %[w01], %[h1], %[a0]\n\t"               \
        "v_mfma_f32_16x16x32_bf16 %[a1], %[w11], %[h1], %[a1]\n\t"               \
        "v_mfma_f32_16x16x32_bf16 %[a2], %[w21], %[h1], %[a2]\n\t"               \
        "v_mfma_f32_16x16x32_bf16 %[a3], %[w31], %[h1], %[a3]\n\t"               \
        "s_nop 7"                                                                \
        : [a0]"=&v"(acc0), [a1]"=&v"(acc1), [a2]"=&v"(acc2), [a3]"=&v"(acc3)     \
        : [w00]"a"(wf[0][0]), [w01]"a"(wf[0][1]),                                \
          [w10]"a"(wf[1][0]), [w11]"a"(wf[1][1]),                                \
          [w20]"a"(wf[2][0]), [w21]"a"(wf[2][1]),                                \
          [w30]"a"(wf[3][0]), [w31]"a"(wf[3][1]),                                \
          [h0]"v"(hb0), [h1]"v"(hb1),                                            \
          [b0]"v"(bc[0]), [b1]"v"(bc[1]), [b2]"v"(bc[2]), [b3]"v"(bc[3]));       \
    floatx4 acc[4] = {acc0, acc1, acc2, acc3};                                   \
    /* r-split: upper half-lanes take partner's r={2,3} */                       \
    float a[4][2];                                                               \
    _Pragma("unroll")                                                            \
    for (int t4 = 0; t4 < 4; ++t4) {                                             \
        const float s2 = __shfl_xor(acc[t4][2], 8);                              \
        const float s3 = __shfl_xor(acc[t4][3], 8);                              \
        a[t4][0] = half ? s2 : acc[t4][0];                                       \
        a[t4][1] = half ? s3 : acc[t4][1];                                       \
    }                                                                            \
    _Pragma("unroll")                                                            \
    for (int z = 0; z < 2; ++z) {                                                \
        const float ig = sigm (fmaf(xv, wihp[0][z], a[0][z]));                   \
        const float fg = sigm (fmaf(xv, wihp[1][z], a[1][z]));                   \
        const float gg = tanhx(fmaf(xv, wihp[2][z], a[2][z]));                   \
        const float og = sigm (fmaf(xv, wihp[3][z], a[3][z]));                   \
        c[z]  = fmaf(fg, c[z], ig * gg);                                         \
        hq[z] = og * tanhx(c[z]);                                                \
    }                                                                            \
    *(WRP) = pk_bf16(hq[0], hq[1]);                                              \
    xv = xnv;                                                                    \
    __syncthreads();                                                             \
} while (0)

    for (int t2 = 0; t2 < 512; t2 += 2) {
        STEP(rd00, rd01, wr1, t2);       // read buf0 (h(t-1)), write buf1
        STEP(rd10, rd11, wr0, t2 + 1);   // read buf1,           write buf0
    }
#undef STEP

    // ---- epilogue: out[b0+m,:] = h_T[m,:] @ W_fc.T + b_fc ----
    // lane's cells: u = 16U + 4lq + 2*half + z
    const int u0 = U * 16 + 4 * lq + 2 * half;
    float p0 = fmaf(hq[0], W_fc[u0],      hq[1] * W_fc[u0 + 1]);
    float p1 = fmaf(hq[0], W_fc[64 + u0], hq[1] * W_fc[64 + u0 + 1]);
    // reduce over lq (shfl_down 32,16) then over the half split (xor 8)
    p0 += __shfl_down(p0, 32);  p0 += __shfl_down(p0, 16);  p0 += __shfl_xor(p0, 8);
    p1 += __shfl_down(p1, 32);  p1 += __shfl_down(p1, 16);  p1 += __shfl_xor(p1, 8);
    if (lane < 8) { red[U][lane][0] = p0; red[U][lane][1] = p1; }
    __syncthreads();
    if (tid < 16) {
        const int mm = tid >> 1, cls = tid & 1;
        const float s = red[0][mm][cls] + red[1][mm][cls] +
                        red[2][mm][cls] + red[3][mm][cls] + b_fc[cls];
        out[(b0 + mm) * 2 + cls] = s;
    }
}

extern "C" void kernel_launch(void* const* d_in, const int* in_sizes, int n_in,
                              void* d_out, int out_size, void* d_ws, size_t ws_size,
                              hipStream_t stream) {
    const float* x    = (const float*)d_in[0];
    const float* W_ih = (const float*)d_in[1];
    const float* W_hh = (const float*)d_in[2];
    const float* b_ih = (const float*)d_in[3];
    const float* b_hh = (const float*)d_in[4];
    const float* W_fc = (const float*)d_in[5];
    const float* b_fc = (const float*)d_in[6];
    float* out = (float*)d_out;

    dim3 grid(256);    // 8 batches per block -> 1 block per CU
    dim3 block(256);   // 4 waves
    hipLaunchKernelGGL(lstm_mfma, grid, block, 0, stream,
                       x, W_ih, W_hh, b_ih, b_hh, W_fc, b_fc, out);
}

// Round 13
// 263.107 us; speedup vs baseline: 1.1676x; 1.1449x over previous
//
#include <hip/hip_runtime.h>

#define LOG2E 1.44269504088896340736f

typedef short    short8  __attribute__((ext_vector_type(8)));
typedef float    floatx4 __attribute__((ext_vector_type(4)));
typedef unsigned uintx4  __attribute__((ext_vector_type(4)));

__device__ __forceinline__ unsigned pk_bf16(float lo, float hi) {
    unsigned r;
    asm("v_cvt_pk_bf16_f32 %0, %1, %2" : "=v"(r) : "v"(lo), "v"(hi));
    return r;
}
__device__ __forceinline__ float sigm(float v) {
    return __builtin_amdgcn_rcpf(1.0f + __builtin_amdgcn_exp2f(-LOG2E * v));
}
__device__ __forceinline__ float tanhx(float v) {
    return 1.0f - 2.0f * __builtin_amdgcn_rcpf(1.0f + __builtin_amdgcn_exp2f(2.0f * LOG2E * v));
}

// One-barrier MFMA LSTM, W/bias staged in LDS (R10 structure, 160us), with the
// r-split DS shuffle replaced by BATCH DUPLICATION: h is written to row m AND
// row m+8, so B-columns 8-15 duplicate 0-7 and each pad-lane receives its own
// copy of the gates in acc registers. The 8 ds_bpermute (~130 cy on the serial
// chain) become 8 v_cndmask with compile-time element indices.
// R12 lesson: opaque inline-asm MFMA blocks defeat the scheduler (258us) —
// builtin MFMAs + LDS-resident W remain the best delivery mechanism.
__global__ void __launch_bounds__(256, 1)
lstm_mfma(const float* __restrict__ x,      // [2048,512]
          const float* __restrict__ W_ih,   // [256]
          const float* __restrict__ W_hh,   // [256,64]
          const float* __restrict__ b_ih,   // [256]
          const float* __restrict__ b_hh,   // [256]
          const float* __restrict__ W_fc,   // [2,64]
          const float* __restrict__ b_fc,   // [2]
          float* __restrict__ out)          // [2048,2]
{
    __shared__ unsigned hlds[2 * 16 * 32];  // 4 KB: 2 bufs, 16 rows x 64 bf16
    __shared__ unsigned wlds[8192];         // 32 KB: W frags, frag-ordered
    __shared__ float    blds[256];          // 1 KB: biasC by (U,t4,lq)
    __shared__ float    red[4][8][2];       // FC cross-wave reduce

    const int tid  = threadIdx.x;
    const int U    = tid >> 6;              // wave 0..3 (u-block)
    const int lane = tid & 63;
    const int l15  = lane & 15;
    const int lq   = lane >> 4;
    const int half = l15 >> 3;              // 0: cells r{0,1}; 1: cells r{2,3}
    const int m    = l15 & 7;               // real batch index
    const int b0   = blockIdx.x * 8;

    // zero both h buffers
    #pragma unroll
    for (int i = 0; i < 4; ++i) hlds[tid + 256 * i] = 0u;

    // ---- stage W_hh A-fragments into LDS (bf16, frag-ordered, lane-linear) ----
    // A-frag for tile (U,t4), k-half f: lane holds row=l15, k=32f+8lq+e (e=0..7)
    #pragma unroll
    for (int t4 = 0; t4 < 4; ++t4) {
        const int grow = t4 * 64 + U * 16 + l15;
        #pragma unroll
        for (int f = 0; f < 2; ++f) {
            const float* p = W_hh + grow * 64 + 32 * f + 8 * lq;
            uintx4 uv;
            uv.x = pk_bf16(p[0], p[1]);
            uv.y = pk_bf16(p[2], p[3]);
            uv.z = pk_bf16(p[4], p[5]);
            uv.w = pk_bf16(p[6], p[7]);
            *(uintx4*)&wlds[(((U * 4 + t4) * 2 + f) * 64 + lane) * 4] = uv;
        }
    }
    // ---- stage biasC into LDS: slot (U,t4,lq), r-vector of 4 ----
    #pragma unroll
    for (int t4 = 0; t4 < 4; ++t4) {
        if (l15 == 0) {
            floatx4 bv;
            #pragma unroll
            for (int r = 0; r < 4; ++r) {
                const int g = t4 * 64 + U * 16 + 4 * lq + r;
                bv[r] = b_ih[g] + b_hh[g];
            }
            *(floatx4*)&blds[(U * 16 + t4 * 4 + lq) * 4] = bv;
        }
    }
    // ---- per-cell W_ih for this lane's 2 cells: r = 2*half + z (8 regs) ----
    float wihp[4][2];
    #pragma unroll
    for (int t4 = 0; t4 < 4; ++t4)
        #pragma unroll
        for (int z = 0; z < 2; ++z)
            wihp[t4][z] = W_ih[t4 * 64 + U * 16 + 4 * lq + 2 * half + z];

    // ---- LDS addressing (word-index XOR swizzle; validated R8-R10) ----
    const int swzr = (l15 & 7) << 2;
    const uintx4* rd00 = (const uintx4*)&hlds[      l15 * 32 + (( 0 + 4 * lq) ^ swzr)];
    const uintx4* rd01 = (const uintx4*)&hlds[      l15 * 32 + ((16 + 4 * lq) ^ swzr)];
    const uintx4* rd10 = (const uintx4*)&hlds[512 + l15 * 32 + (( 0 + 4 * lq) ^ swzr)];
    const uintx4* rd11 = (const uintx4*)&hlds[512 + l15 * 32 + ((16 + 4 * lq) ^ swzr)];
    // write: row m, word (8U + 2lq + half) ^ (m<<2) — 2-way banked (free).
    // Duplicate goes to row m+8 = +256 words, same swizzle ((m+8)&7 == m&7).
    unsigned* wr0 = &hlds[      m * 32 + ((8 * U + 2 * lq + half) ^ (m << 2))];
    unsigned* wr1 = &hlds[512 + m * 32 + ((8 * U + 2 * lq + half) ^ (m << 2))];

    float c[2]  = {0.f, 0.f};
    float hq[2] = {0.f, 0.f};

    const float* xrow = x + (long)(b0 + m) * 512;
    float xv = xrow[0];                      // current-step x (prefetched)

    __syncthreads();

#define STEP(RD0, RD1, WRP, T) do {                                              \
    const int   tn  = ((T) < 511) ? (T) + 1 : 511;                               \
    const float xnv = xrow[tn];              /* prefetch next step's x */        \
    floatx4 bc[4];                                                               \
    _Pragma("unroll")                                                            \
    for (int t4 = 0; t4 < 4; ++t4)                                               \
        bc[t4] = *(const floatx4*)&blds[(U * 16 + t4 * 4 + lq) * 4];             \
    short8 hb0 = __builtin_bit_cast(short8, *(RD0));                             \
    short8 hb1 = __builtin_bit_cast(short8, *(RD1));                             \
    short8 wf[4][2];                                                             \
    _Pragma("unroll")                                                            \
    for (int t4 = 0; t4 < 4; ++t4)                                               \
        _Pragma("unroll")                                                        \
        for (int f = 0; f < 2; ++f)                                              \
            wf[t4][f] = __builtin_bit_cast(short8,                               \
                *(const uintx4*)&wlds[(((U * 4 + t4) * 2 + f) * 64 + lane) * 4]);\
    floatx4 acc[4];                                                              \
    _Pragma("unroll")                                                            \
    for (int t4 = 0; t4 < 4; ++t4) {                                             \
        acc[t4] = __builtin_amdgcn_mfma_f32_16x16x32_bf16(wf[t4][0], hb0,        \
                                                          bc[t4], 0, 0, 0);      \
        acc[t4] = __builtin_amdgcn_mfma_f32_16x16x32_bf16(wf[t4][1], hb1,        \
                                                          acc[t4], 0, 0, 0);     \
    }                                                                            \
    /* r-split WITHOUT shuffle: pad-lane's acc duplicates its real batch */      \
    float a[4][2];                                                               \
    _Pragma("unroll")                                                            \
    for (int t4 = 0; t4 < 4; ++t4) {                                             \
        a[t4][0] = half ? acc[t4][2] : acc[t4][0];                               \
        a[t4][1] = half ? acc[t4][3] : acc[t4][1];                               \
    }                                                                            \
    _Pragma("unroll")                                                            \
    for (int z = 0; z < 2; ++z) {                                                \
        const float ig = sigm (fmaf(xv, wihp[0][z], a[0][z]));                   \
        const float fg = sigm (fmaf(xv, wihp[1][z], a[1][z]));                   \
        const float gg = tanhx(fmaf(xv, wihp[2][z], a[2][z]));                   \
        const float og = sigm (fmaf(xv, wihp[3][z], a[3][z]));                   \
        c[z]  = fmaf(fg, c[z], ig * gg);                                         \
        hq[z] = og * tanhx(c[z]);                                                \
    }                                                                            \
    {                                                                            \
        const unsigned pkh = pk_bf16(hq[0], hq[1]);                              \
        *(WRP)         = pkh;                                                    \
        *((WRP) + 256) = pkh;   /* duplicate row m+8 */                          \
    }                                                                            \
    xv = xnv;                                                                    \
    __syncthreads();                                                             \
} while (0)

    for (int t2 = 0; t2 < 512; t2 += 2) {
        STEP(rd00, rd01, wr1, t2);       // read buf0 (h(t-1)), write buf1
        STEP(rd10, rd11, wr0, t2 + 1);   // read buf1,           write buf0
    }
#undef STEP

    // ---- epilogue: out[b0+m,:] = h_T[m,:] @ W_fc.T + b_fc ----
    // lane's cells: u = 16U + 4lq + 2*half + z
    const int u0 = U * 16 + 4 * lq + 2 * half;
    float p0 = fmaf(hq[0], W_fc[u0],      hq[1] * W_fc[u0 + 1]);
    float p1 = fmaf(hq[0], W_fc[64 + u0], hq[1] * W_fc[64 + u0 + 1]);
    // reduce over lq (shfl_down 32,16) then over the half split (xor 8)
    p0 += __shfl_down(p0, 32);  p0 += __shfl_down(p0, 16);  p0 += __shfl_xor(p0, 8);
    p1 += __shfl_down(p1, 32);  p1 += __shfl_down(p1, 16);  p1 += __shfl_xor(p1, 8);
    if (lane < 8) { red[U][lane][0] = p0; red[U][lane][1] = p1; }
    __syncthreads();
    if (tid < 16) {
        const int mm = tid >> 1, cls = tid & 1;
        const float s = red[0][mm][cls] + red[1][mm][cls] +
                        red[2][mm][cls] + red[3][mm][cls] + b_fc[cls];
        out[(b0 + mm) * 2 + cls] = s;
    }
}

extern "C" void kernel_launch(void* const* d_in, const int* in_sizes, int n_in,
                              void* d_out, int out_size, void* d_ws, size_t ws_size,
                              hipStream_t stream) {
    const float* x    = (const float*)d_in[0];
    const float* W_ih = (const float*)d_in[1];
    const float* W_hh = (const float*)d_in[2];
    const float* b_ih = (const float*)d_in[3];
    const float* b_hh = (const float*)d_in[4];
    const float* W_fc = (const float*)d_in[5];
    const float* b_fc = (const float*)d_in[6];
    float* out = (float*)d_out;

    dim3 grid(256);    // 8 batches per block -> 1 block per CU
    dim3 block(256);   // 4 waves
    hipLaunchKernelGGL(lstm_mfma, grid, block, 0, stream,
                       x, W_ih, W_hh, b_ih, b_hh, W_fc, b_fc, out);
}